// Round 4
// baseline (919.022 us; speedup 1.0000x reference)
//
#include <hip/hip_runtime.h>
#include <math.h>

#define BB 16
#define TT 512
#define IND 128
#define HH 256
#define DD 8
#define EPSF 1e-5f

typedef _Float16 h8_t __attribute__((ext_vector_type(8)));
typedef float f32x4 __attribute__((ext_vector_type(4)));

#define HROWB 576          // bytes per batch-row of H in LDS (144 dwords)
#define TEAMB (8 * HROWB)  // one buffer for one team: 8 batch-rows = 4608 B

__device__ __forceinline__ float fast_tanh(float x) {
    // exp->inf gives 1, exp->0 gives -1; no clamp needed (verified r1/r2)
    const float e = __expf(2.f * x);
    return 1.f - __fdividef(2.f, e + 1.f);
}

// ---------------- K1: x_proj[b,t,j] = y[b,t,:]·W_ih[j,:] + b_ih[j] + b_hh[j] ----------------
__global__ __launch_bounds__(512, 4) void xproj_kernel(
    const float* __restrict__ y, const float* __restrict__ W_ih,
    const float* __restrict__ b_ih, const float* __restrict__ b_hh,
    float* __restrict__ xp)
{
    __shared__ __align__(16) float ylds[IND];
    const int tid = threadIdx.x;
    const int j = tid >> 1;
    const int k4 = (tid & 1) * 4;

    float4 w[16];
    const float* wr = W_ih + (size_t)j * IND + k4;
#pragma unroll
    for (int i = 0; i < 16; ++i) w[i] = *(const float4*)(wr + i * 8);
#pragma unroll
    for (int i = 0; i < 16; ++i)
        asm volatile("" : "+v"(w[i].x), "+v"(w[i].y), "+v"(w[i].z), "+v"(w[i].w));
    const float bias = b_ih[j] + b_hh[j];

    const int row0 = blockIdx.x * 16;
    for (int r = 0; r < 16; ++r) {
        const int row = row0 + r;
        if (tid < IND / 4) ((float4*)ylds)[tid] = ((const float4*)(y + (size_t)row * IND))[tid];
        __syncthreads();
        float a0 = 0.f, a1 = 0.f, a2 = 0.f, a3 = 0.f;
#pragma unroll
        for (int i = 0; i < 16; ++i) {
            const float4 hv = *(const float4*)(ylds + i * 8 + k4);
            a0 = fmaf(hv.x, w[i].x, a0);
            a1 = fmaf(hv.y, w[i].y, a1);
            a2 = fmaf(hv.z, w[i].z, a2);
            a3 = fmaf(hv.w, w[i].w, a3);
        }
        float acc = (a0 + a1) + (a2 + a3);
        acc += __shfl_xor(acc, 1);
        if ((tid & 1) == 0) xp[(size_t)row * HH + j] = acc + bias;
        __syncthreads();
    }
}

// ---------------- K2: MFMA RNN scan (block 0) + prec zero-fill (blocks 1..) ----------------
// 512 threads = 8 waves = 2 teams x 4 waves (2 waves/SIMD -> mutual latency hiding).
// Team T (w>>2): batches 8T..8T+7 (independent chains). Wave wt (w&3): j in [64wt,64wt+64).
// Per wave/step: acc[mt] initialized from xp (MFMA C-in), 4 mt-tiles x 8 chained
// mfma_f32_16x16x32_f16 over K=256 (fragment convention HW-proven in r2).
// B-rows exist for 8 batches; lanes lr>=8 read row lr&7 (same-addr broadcast, free) so
// their MFMA columns n>=8 equal batch (lr-8)'s REAL results -> lanes lr<8 keep acc{0,1}
// (j-tiles 0,1), lanes lr>=8 keep acc{2,3} (j-tiles 2,3): full coverage, no repacking,
// 8 tanh/lane. Row pitch 576 B => 64-lane b128 reads hit distinct mod-128 dword slots
// (conflict-free). lgkm-only barrier keeps the 1-step xp prefetch in flight.
__global__ __launch_bounds__(512, 2) void scan_fill_kernel(
    const float* __restrict__ xp, const float* __restrict__ W_hh,
    float* __restrict__ enc, float* __restrict__ prec)
{
    if (blockIdx.x != 0) {
        const size_t n4 = (size_t)BB * DD * TT * TT / 4;
        const f32x4 z = {0.f, 0.f, 0.f, 0.f};
        f32x4* p4 = (f32x4*)prec;
        size_t idx = (size_t)(blockIdx.x - 1) * blockDim.x + threadIdx.x;
        const size_t stride = (size_t)(gridDim.x - 1) * blockDim.x;
        for (; idx < n4; idx += stride) p4[idx] = z;
        return;
    }

    const int tid = threadIdx.x;
    const int w   = tid >> 6;     // wave 0..7
    const int T   = w >> 2;       // team 0/1: batches 8T..8T+7
    const int wt  = w & 3;        // wave-in-team: j in [64wt, 64wt+64)
    const int l   = tid & 63;
    const int lr  = l & 15;       // MFMA n (batch col) / A row-in-tile
    const int lh  = l >> 4;       // 0..3 k-group
    const int row = lr & 7;       // LDS batch-row this lane reads/writes
    const int bg  = 8 * T + row;  // global batch index

    __shared__ __align__(16) char hlds[2 * 2 * TEAMB];  // [team][buf][8 rows x 576 B]

    // ---- A fragments: af[mt][kt] = W_hh[64wt+16mt+lr][32kt+8lh+e], pinned (128 VGPR) ----
    h8_t af[4][8];
#pragma unroll
    for (int mt = 0; mt < 4; ++mt) {
        const float* wrow = W_hh + (size_t)(64 * wt + 16 * mt + lr) * HH;
#pragma unroll
        for (int kt = 0; kt < 8; ++kt) {
            const float* p = wrow + 32 * kt + 8 * lh;
            const f32x4 f0 = *(const f32x4*)(p);
            const f32x4 f1 = *(const f32x4*)(p + 4);
            h8_t v;
            v[0] = (_Float16)f0[0]; v[1] = (_Float16)f0[1];
            v[2] = (_Float16)f0[2]; v[3] = (_Float16)f0[3];
            v[4] = (_Float16)f1[0]; v[5] = (_Float16)f1[1];
            v[6] = (_Float16)f1[2]; v[7] = (_Float16)f1[3];
            af[mt][kt] = v;
        }
    }
#pragma unroll
    for (int mt = 0; mt < 4; ++mt)
#pragma unroll
        for (int kt = 0; kt < 8; ++kt) {
            int4 t4 = __builtin_bit_cast(int4, af[mt][kt]);
            asm volatile("" : "+v"(t4.x), "+v"(t4.y), "+v"(t4.z), "+v"(t4.w));
            af[mt][kt] = __builtin_bit_cast(h8_t, t4);
        }

    // zero-init buf0 of both teams (h0 = 0): 2 x 4608 B = 576 f32x4 stores
    {
        const f32x4 z = {0.f, 0.f, 0.f, 0.f};
        for (int i = tid; i < 576; i += 512) {
            const int t2 = (i >= 288);
            *(f32x4*)(hlds + t2 * (2 * TEAMB) + (i - t2 * 288) * 16) = z;
        }
    }

    const char* hrd = hlds + T * (2 * TEAMB);
    char* hwr = (char*)hrd + TEAMB;

    const bool lo = (lr < 8);
    const int jb = 64 * wt + (lo ? 0 : 32) + 4 * lh;  // first owned j (tile p0), p0+1 at +16

    // 1-step rotating xp prefetch: XC used as MFMA C-in this step
    f32x4 xa[4], xb[4];
#pragma unroll
    for (int mt = 0; mt < 4; ++mt)
        xa[mt] = *(const f32x4*)(xp + ((size_t)bg * TT + 0) * HH + 64 * wt + 16 * mt + 4 * lh);

    __syncthreads();

#define SCAN_STEP(TSTEP, XC, XN)                                                          \
    {                                                                                     \
        const int t_ = (TSTEP);                                                           \
        const int tp_ = (t_ < TT - 1) ? t_ + 1 : t_;                                      \
        _Pragma("unroll")                                                                 \
        for (int mt = 0; mt < 4; ++mt)                                                    \
            XN[mt] = *(const f32x4*)(xp + ((size_t)bg * TT + tp_) * HH +                  \
                                     64 * wt + 16 * mt + 4 * lh);                         \
        h8_t bf[8];                                                                       \
        _Pragma("unroll")                                                                 \
        for (int kt = 0; kt < 8; ++kt)                                                    \
            bf[kt] = *(const h8_t*)(hrd + row * HROWB + kt * 64 + lh * 16);               \
        f32x4 a0 = XC[0], a1 = XC[1], a2 = XC[2], a3 = XC[3];                             \
        _Pragma("unroll")                                                                 \
        for (int kt = 0; kt < 8; ++kt) {                                                  \
            a0 = __builtin_amdgcn_mfma_f32_16x16x32_f16(af[0][kt], bf[kt], a0, 0, 0, 0);  \
            a1 = __builtin_amdgcn_mfma_f32_16x16x32_f16(af[1][kt], bf[kt], a1, 0, 0, 0);  \
            a2 = __builtin_amdgcn_mfma_f32_16x16x32_f16(af[2][kt], bf[kt], a2, 0, 0, 0);  \
            a3 = __builtin_amdgcn_mfma_f32_16x16x32_f16(af[3][kt], bf[kt], a3, 0, 0, 0);  \
        }                                                                                 \
        f32x4 u0, u1;                                                                     \
        _Pragma("unroll")                                                                 \
        for (int r = 0; r < 4; ++r) {                                                     \
            u0[r] = lo ? a0[r] : a2[r];                                                   \
            u1[r] = lo ? a1[r] : a3[r];                                                   \
        }                                                                                 \
        f32x4 s0, s1;                                                                     \
        _Pragma("unroll")                                                                 \
        for (int r = 0; r < 4; ++r) { s0[r] = fast_tanh(u0[r]); s1[r] = fast_tanh(u1[r]); } \
        float* eb = enc + ((size_t)bg * TT + t_) * HH + jb;                               \
        *(f32x4*)(eb)      = s0;                                                          \
        *(f32x4*)(eb + 16) = s1;                                                          \
        int2 w01, w23;                                                                    \
        w01.x = __builtin_bit_cast(int, __builtin_amdgcn_cvt_pkrtz(s0[0], s0[1]));        \
        w01.y = __builtin_bit_cast(int, __builtin_amdgcn_cvt_pkrtz(s0[2], s0[3]));        \
        w23.x = __builtin_bit_cast(int, __builtin_amdgcn_cvt_pkrtz(s1[0], s1[1]));        \
        w23.y = __builtin_bit_cast(int, __builtin_amdgcn_cvt_pkrtz(s1[2], s1[3]));        \
        *(int2*)(hwr + row * HROWB + jb * 2)      = w01;                                  \
        *(int2*)(hwr + row * HROWB + jb * 2 + 32) = w23;                                  \
        asm volatile("s_waitcnt lgkmcnt(0)\n\ts_barrier" ::: "memory");                   \
        { const char* tmp_ = hrd; hrd = hwr; hwr = (char*)tmp_; }                         \
    }

    for (int tb = 0; tb < TT; tb += 2) {
        SCAN_STEP(tb, xa, xb)
        SCAN_STEP(tb + 1, xb, xa)
    }
#undef SCAN_STEP
}

// ---------------- K3: heads + tridiagonal fill ----------------
__global__ __launch_bounds__(256) void head_kernel(
    const float* __restrict__ enc,
    const float* __restrict__ W_mean, const float* __restrict__ b_mean,
    const float* __restrict__ W_bd, const float* __restrict__ b_bd,
    float* __restrict__ mean_out, float* __restrict__ prec)
{
    const int b = blockIdx.x >> 6;
    const int t0 = (blockIdx.x & 63) * 8;
    __shared__ __align__(16) float erow[9][HH];  // rows t0-1 .. t0+7
    __shared__ float vals[8][32];

    const int tid = threadIdx.x;
    {
        // row t0-1 (for t0==0,b==0 this reads the tail of xp — harmless, discarded)
        const float4* src = (const float4*)(enc + ((size_t)b * TT + t0) * HH - HH);
        float4* dst = (float4*)erow;
        for (int i = tid; i < 9 * (HH / 4); i += 256) dst[i] = src[i];
    }

    const int g = tid >> 3, m = tid & 7;
    const float* wrow;
    float bias;
    if (g < 8)       { wrow = W_mean + (size_t)g * HH;      bias = b_mean[g]; }
    else if (g < 24) { wrow = W_bd + (size_t)(g - 8) * HH;  bias = b_bd[g - 8]; }
    else             { wrow = W_bd + (size_t)(g - 16) * HH; bias = b_bd[g - 16]; }

    float4 wv[8];
#pragma unroll
    for (int i = 0; i < 8; ++i) wv[i] = ((const float4*)wrow)[m * 8 + i];

    __syncthreads();

    for (int r = 0; r < 8; ++r) {
        const float* src = (g >= 24) ? erow[r] : erow[r + 1];
        float acc = 0.f;
#pragma unroll
        for (int i = 0; i < 8; ++i) {
            const float4 hv = ((const float4*)src)[m * 8 + i];
            acc += wv[i].x * hv.x + wv[i].y * hv.y + wv[i].z * hv.z + wv[i].w * hv.w;
        }
        acc += __shfl_xor(acc, 1);
        acc += __shfl_xor(acc, 2);
        acc += __shfl_xor(acc, 4);
        if (m == 0) vals[r][g] = acc + bias;
    }
    __syncthreads();

    // write phase: 256 threads = 8 r-slots x 32 lanes
    const int r = tid >> 5, s = tid & 31;
    const int t = t0 + r;
    if (s < DD) {
        mean_out[((size_t)b * TT + t) * DD + s] = vals[r][s];
    } else if (s < 2 * DD) {
        const int d = s - DD;
        const float diag = vals[r][8 + d];
        const float off  = vals[r][16 + d];
        const float offp = (t > 0) ? vals[r][24 + d] : 0.f;
        const size_t rowbase = (((size_t)b * DD + d) * TT + t) * TT;
        prec[rowbase + t] = diag * diag + offp * offp + EPSF;
        if (t < TT - 1) {
            const float sv = diag * off;
            prec[rowbase + t + 1] = sv;                                 // (t, t+1)
            prec[(((size_t)b * DD + d) * TT + (t + 1)) * TT + t] = sv;  // (t+1, t)
        }
    }
}

extern "C" void kernel_launch(void* const* d_in, const int* in_sizes, int n_in,
                              void* d_out, int out_size, void* d_ws, size_t ws_size,
                              hipStream_t stream) {
    const float* y      = (const float*)d_in[0];
    const float* W_ih   = (const float*)d_in[1];
    const float* W_hh   = (const float*)d_in[2];
    const float* b_ih   = (const float*)d_in[3];
    const float* b_hh   = (const float*)d_in[4];
    const float* W_mean = (const float*)d_in[5];
    const float* b_mean = (const float*)d_in[6];
    const float* W_bd   = (const float*)d_in[7];
    const float* b_bd   = (const float*)d_in[8];

    float* out  = (float*)d_out;
    float* mean = out;                              // B*T*D floats
    float* prec = out + (size_t)BB * TT * DD;       // B*D*T*T floats

    float* xp  = (float*)d_ws;                      // B*T*H floats = 8 MB
    float* enc = xp + (size_t)BB * TT * HH;         // B*T*H floats = 8 MB

    xproj_kernel<<<512, 512, 0, stream>>>(y, W_ih, b_ih, b_hh, xp);
    scan_fill_kernel<<<1008, 512, 0, stream>>>(xp, W_hh, enc, prec);
    head_kernel<<<1024, 256, 0, stream>>>(enc, W_mean, b_mean, W_bd, b_bd, mean, prec);
}